// Round 4
// baseline (672.950 us; speedup 1.0000x reference)
//
#include <hip/hip_runtime.h>
#include <math.h>

// SimpleBICEPLayer fused kernel, round 4.
//
//   fb[b]          = sigmoid(x[b,:] . W_fb + b_fb)
//   endpoints[b,p] = sqrt(dt) * ( 0.5 * sum_s noise[b,p,s]
//                                + fb[b] * sum_s g^s * noise[b,p,s] ),  g = exp(-0.002)
//   out[b,o]       = sum_p endpoints[b,p] * W_agg[o,p] + b_agg[o]
//
// Round-4 change: barrier-free per-wave streaming. Round 3 issued prefetch
// loads BEFORE __syncthreads -> compiler's s_waitcnt vmcnt(0) at the barrier
// drained them every chunk (full HBM latency serialized per chunk: 316 us,
// VALUBusy 3%). Now each wave owns 4 batch rows and a private 12.8 KB LDS
// staging buffer; ds_write/ds_read are intra-wave (in-order DS FIFO), so the
// hot loop has NO barrier and NO vmcnt(0) drain. Register prefetch (13 x
// float4) gets precise per-register vmcnt waits with a full iteration in
// flight. One __syncthreads total, before the validated MFMA epilogue.
// NO d_ws use (harness poisons it concurrently with replays - round 2).

#define B_TOTAL 8192
#define D_IN    512
#define D_OUT   1024
#define NP      256
#define NS      50
#define BT      16
#define THREADS 256
#define EP_STRIDE 264              // 256 + 8 pad

#define SQRT_DT 0.14142135623730951f
#define G_STEP  0.99800199866f     // exp(-0.002)
#define G_STEP2 0.99600798935f     // exp(-0.004)

typedef __bf16 bf16x8 __attribute__((ext_vector_type(8)));
typedef float  f32x4  __attribute__((ext_vector_type(4)));

__device__ __forceinline__ unsigned short f2bf(float f) {
    unsigned u = __float_as_uint(f);
    return (unsigned short)((u + 0x7FFFu + ((u >> 16) & 1u)) >> 16);
}

__global__ __launch_bounds__(THREADS, 2) void bicep_main(
    const float* __restrict__ x,
    const float* __restrict__ Wfb,
    const float* __restrict__ bfb,
    const float* __restrict__ Wagg,
    const float* __restrict__ bagg,
    const float* __restrict__ noise,
    float* __restrict__ out)
{
    __shared__ __align__(16) float4 stage[4][800];                 // 51200 B, per-wave
    __shared__ __align__(16) unsigned short ep_bf[BT * EP_STRIDE]; // 8448 B
    __shared__ float fb_s[BT];
    __shared__ float bagg_s[D_OUT];                                // 4096 B

    const int tid  = threadIdx.x;
    const int lane = tid & 63;
    const int wave = tid >> 6;
    const int b0   = blockIdx.x * BT;

    // ---- Phase A: bias table + feedback sigmoid. Wave w computes rows
    // w*4..w*4+3 and is the ONLY consumer of those fb values -> no barrier. ----
    {
        #pragma unroll
        for (int i = 0; i < D_OUT / THREADS; ++i)
            bagg_s[i * THREADS + tid] = bagg[i * THREADS + tid];

        const float bf_b = bfb[0];
        const float4* wf = (const float4*)Wfb + lane * 2;
        float4 wa = wf[0], wb = wf[1];
        #pragma unroll
        for (int rr = 0; rr < 4; ++rr) {
            int row = wave * 4 + rr;
            const float4* xr = (const float4*)(x + (size_t)(b0 + row) * D_IN) + lane * 2;
            float4 xa = xr[0], xb = xr[1];
            float p = xa.x*wa.x + xa.y*wa.y + xa.z*wa.z + xa.w*wa.w
                    + xb.x*wb.x + xb.y*wb.y + xb.z*wb.z + xb.w*wb.w;
            #pragma unroll
            for (int mm = 32; mm >= 1; mm >>= 1) p += __shfl_xor(p, mm, 64);
            if (lane == 0) fb_s[row] = 1.0f / (1.0f + __expf(-(p + bf_b)));
        }
    }

    // ---- Per-wave streaming: 16 iterations x 64 (row,p)-runs (12.8 KB).
    // Wave w's noise span: floats [(b0+w*4)*12800, +51200) contiguous;
    // iteration c covers float4s [c*800, (c+1)*800) of that span. ----
    {
        float4* st = stage[wave];
        const float4* base = (const float4*)noise + (size_t)(b0 + wave * 4) * 3200;

        float4 v[13];
        {
            const float4* p0 = base;
            #pragma unroll
            for (int i = 0; i < 12; ++i) v[i] = p0[i * 64 + lane];
            v[12] = p0[768 + (lane & 31)];
        }

        for (int c = 0; c < 16; ++c) {
            // stage chunk c (waits precisely on v's vmcnt - a full iteration old)
            #pragma unroll
            for (int i = 0; i < 12; ++i) st[i * 64 + lane] = v[i];
            st[768 + (lane & 31)] = v[12];   // duplicate store, same value - benign

            // prefetch chunk c+1 (register-held, stays in flight through compute)
            if (c + 1 < 16) {
                const float4* pn = base + (size_t)(c + 1) * 800;
                #pragma unroll
                for (int i = 0; i < 12; ++i) v[i] = pn[i * 64 + lane];
                v[12] = pn[768 + (lane & 31)];
            }

            // lane's run: 50 floats at word offset lane*50 (stride 50 % 32 ->
            // 2-way bank aliasing = free). Horner for sum g^s * n[s].
            const float2* run = (const float2*)((const float*)st + lane * 50);
            float s0 = 0.f, t1 = 0.f;
            #pragma unroll
            for (int j = 24; j >= 0; --j) {
                float2 n2 = run[j];
                s0 += n2.x + n2.y;
                t1 = fmaf(t1, G_STEP2, fmaf(n2.y, G_STEP, n2.x));
            }
            const int lr = wave * 4 + (c >> 2);
            float ep = SQRT_DT * fmaf(fb_s[lr], t1, 0.5f * s0);
            ep_bf[lr * EP_STRIDE + (c & 3) * 64 + lane] = f2bf(ep);
        }
    }
    __syncthreads();

    // ---- Epilogue (validated round 3): out[16 x 1024] = ep @ W^T via bf16
    // MFMA. A-frag: lane holds A[m=lane&15][k=(lane>>4)*8+j];
    // B-frag: lane holds B[k][n=lane&15] = W[O*16+n][k];
    // C/D: col=lane&15, row=(lane>>4)*4+reg. W_agg fp32 from L2. ----
    {
        const int m  = lane & 15;
        const int kg = lane >> 4;

        bf16x8 afr[8];
        #pragma unroll
        for (int ks = 0; ks < 8; ++ks)
            afr[ks] = *(const bf16x8*)&ep_bf[m * EP_STRIDE + ks * 32 + kg * 8];

        #pragma unroll 2
        for (int i = 0; i < 16; ++i) {
            int O = wave * 16 + i;               // o-tile: cols O*16..O*16+15
            const float* wp = Wagg + (size_t)(O * 16 + m) * NP + kg * 8;
            f32x4 acc = {0.f, 0.f, 0.f, 0.f};
            #pragma unroll
            for (int ks = 0; ks < 8; ++ks) {
                float4 wa = *(const float4*)(wp + ks * 32);
                float4 wb = *(const float4*)(wp + ks * 32 + 4);
                bf16x8 bfr = { (__bf16)wa.x, (__bf16)wa.y, (__bf16)wa.z, (__bf16)wa.w,
                               (__bf16)wb.x, (__bf16)wb.y, (__bf16)wb.z, (__bf16)wb.w };
                acc = __builtin_amdgcn_mfma_f32_16x16x32_bf16(afr[ks], bfr, acc, 0, 0, 0);
            }
            float bias = bagg_s[O * 16 + m];
            #pragma unroll
            for (int r = 0; r < 4; ++r)
                out[(size_t)(b0 + kg * 4 + r) * D_OUT + O * 16 + m] = acc[r] + bias;
        }
    }
}

extern "C" void kernel_launch(void* const* d_in, const int* in_sizes, int n_in,
                              void* d_out, int out_size, void* d_ws, size_t ws_size,
                              hipStream_t stream) {
    const float* x     = (const float*)d_in[0];
    const float* Wfb   = (const float*)d_in[1];
    const float* bfb   = (const float*)d_in[2];
    const float* Wagg  = (const float*)d_in[3];
    const float* bagg  = (const float*)d_in[4];
    const float* noise = (const float*)d_in[5];
    float* out = (float*)d_out;
    (void)d_ws; (void)ws_size;

    bicep_main<<<dim3(B_TOTAL / BT), dim3(THREADS), 0, stream>>>(
        x, Wfb, bfb, Wagg, bagg, noise, out);
}